// Round 2
// baseline (31339.343 us; speedup 1.0000x reference)
//
#include <hip/hip_runtime.h>
#include <hip/hip_bf16.h>

// Problem sizes (fixed by reference)
#define Bd 128
#define Sd 1024
#define Id 512
#define Hd 512

// Scan decomposition: 8 blocks, one per 16-batch group; no inter-block traffic
#define NG 8
#define BB 16   // batches per group

typedef __attribute__((ext_vector_type(8))) short short8;   // 8 bf16 (4 VGPRs)
typedef __attribute__((ext_vector_type(4))) float f32x4;

__device__ __forceinline__ unsigned int bf16_rn_bits(float x){
  unsigned int bx = __float_as_uint(x);
  return (bx + 0x7FFFu + ((bx >> 16) & 1u)) >> 16;   // round-to-nearest-even
}
__device__ __forceinline__ void bf16_split(float x, unsigned short& hi, unsigned short& lo){
  unsigned int hb = bf16_rn_bits(x);
  float hf = __uint_as_float(hb << 16);
  hi = (unsigned short)hb;
  lo = (unsigned short)bf16_rn_bits(x - hf);
}

// ---------------------------------------------------------------------------
// K1: xh = inputs @ W_ih + bias_h  (3-term bf16-split MFMA; out consumed
//     in-place by the scan).  Tile 128x128, BK=64, 256 threads / 4 waves.
// ---------------------------------------------------------------------------
__global__ __launch_bounds__(256) void k_xh(const float* __restrict__ X,
                                            const float* __restrict__ W,
                                            const float* __restrict__ bias,
                                            float* __restrict__ out)
{
  const int bidm = blockIdx.x >> 2;   // 1024 row-tiles of BS=131072
  const int bidn = blockIdx.x & 3;    // 4 col-tiles of H=512 (consecutive share A)
  const int tid  = threadIdx.x;
  const int lane = tid & 63;
  const int wv   = tid >> 6;
  const int wr   = wv >> 1, wc = wv & 1;       // wave -> 64x64 quadrant
  const int n16  = lane & 15, kq = lane >> 4;  // frag coords

  __shared__ __align__(16) unsigned short Ah[128 * 64];  // [m][k] swizzled
  __shared__ __align__(16) unsigned short Al[128 * 64];
  __shared__ __align__(16) unsigned short Bh[128 * 64];  // [n][k] swizzled
  __shared__ __align__(16) unsigned short Bl[128 * 64];

  f32x4 acc[4][4];
  #pragma unroll
  for (int i = 0; i < 4; ++i)
    #pragma unroll
    for (int j = 0; j < 4; ++j) acc[i][j] = (f32x4){0.f, 0.f, 0.f, 0.f};

  const float* Xb = X + (size_t)bidm * 128 * Id;
  const float* Wb = W + bidn * 128;

  for (int k0 = 0; k0 < Id; k0 += 64) {
    // ---- stage A: 128 rows x 64 k fp32 -> hi/lo bf16, XOR-swizzled ----
    #pragma unroll
    for (int f = 0; f < 8; ++f) {
      int idx = f * 256 + tid;                 // 0..2047 float4s
      int m = idx >> 4, kc = (idx & 15) * 4;
      float4 v = *(const float4*)(Xb + (size_t)m * Id + k0 + kc);
      unsigned short h0,l0,h1,l1,h2,l2,h3,l3;
      bf16_split(v.x,h0,l0); bf16_split(v.y,h1,l1);
      bf16_split(v.z,h2,l2); bf16_split(v.w,h3,l3);
      unsigned long long ph = (unsigned long long)h0 | ((unsigned long long)h1<<16)
                            | ((unsigned long long)h2<<32) | ((unsigned long long)h3<<48);
      unsigned long long pl = (unsigned long long)l0 | ((unsigned long long)l1<<16)
                            | ((unsigned long long)l2<<32) | ((unsigned long long)l3<<48);
      int off = (m * 128 + kc * 2) ^ ((m & 7) << 4);
      *(unsigned long long*)((char*)Ah + off) = ph;
      *(unsigned long long*)((char*)Al + off) = pl;
    }
    // ---- stage B: 64 k x 128 n fp32 -> transposed [n][k] hi/lo, swizzled ----
    #pragma unroll
    for (int f = 0; f < 8; ++f) {
      int idx = f * 256 + tid;                 // 0..2047 float4s
      int kr = idx >> 5, nc = (idx & 31) * 4;
      float4 v = *(const float4*)(Wb + (size_t)(k0 + kr) * Hd + nc);
      float vv[4] = {v.x, v.y, v.z, v.w};
      #pragma unroll
      for (int q = 0; q < 4; ++q) {
        unsigned short h, l; bf16_split(vv[q], h, l);
        int n = nc + q;
        int off = (n * 128 + kr * 2) ^ ((n & 7) << 4);
        *(unsigned short*)((char*)Bh + off) = h;
        *(unsigned short*)((char*)Bl + off) = l;
      }
    }
    __syncthreads();
    // ---- MFMA: 3-term split accumulated into one chain per (mt,nt) ----
    #pragma unroll
    for (int kt = 0; kt < 2; ++kt) {
      short8 amh[4], aml[4];
      #pragma unroll
      for (int mt = 0; mt < 4; ++mt) {
        int m = wr * 64 + mt * 16 + n16;
        int off = (m * 128 + kt * 64 + kq * 16) ^ ((m & 7) << 4);
        amh[mt] = *(short8*)((char*)Ah + off);
        aml[mt] = *(short8*)((char*)Al + off);
      }
      #pragma unroll
      for (int ntl = 0; ntl < 4; ++ntl) {
        int n = wc * 64 + ntl * 16 + n16;
        int off = (n * 128 + kt * 64 + kq * 16) ^ ((n & 7) << 4);
        short8 bh = *(short8*)((char*)Bh + off);
        short8 bl = *(short8*)((char*)Bl + off);
        #pragma unroll
        for (int mt = 0; mt < 4; ++mt) {
          acc[mt][ntl] = __builtin_amdgcn_mfma_f32_16x16x32_bf16(amh[mt], bh, acc[mt][ntl], 0,0,0);
          acc[mt][ntl] = __builtin_amdgcn_mfma_f32_16x16x32_bf16(amh[mt], bl, acc[mt][ntl], 0,0,0);
          acc[mt][ntl] = __builtin_amdgcn_mfma_f32_16x16x32_bf16(aml[mt], bh, acc[mt][ntl], 0,0,0);
        }
      }
    }
    __syncthreads();
  }
  // ---- epilogue: + bias, fp32 store ----
  float bj[4];
  #pragma unroll
  for (int ntl = 0; ntl < 4; ++ntl) bj[ntl] = bias[bidn * 128 + wc * 64 + ntl * 16 + n16];
  #pragma unroll
  for (int mt = 0; mt < 4; ++mt)
    #pragma unroll
    for (int ntl = 0; ntl < 4; ++ntl)
      #pragma unroll
      for (int r = 0; r < 4; ++r) {
        size_t m = (size_t)bidm * 128 + wr * 64 + mt * 16 + kq * 4 + r;
        int n = bidn * 128 + wc * 64 + ntl * 16 + n16;
        out[m * Hd + n] = acc[mt][ntl][r] + bj[ntl];
      }
}

// ---------------------------------------------------------------------------
// K1b: xr = inputs @ W_ir + b_r ; xi = inputs @ W_ii + b_i   (one wave per row)
// ---------------------------------------------------------------------------
__global__ __launch_bounds__(256) void k_xri(const float* __restrict__ X,
                                             const float* __restrict__ Wir,
                                             const float* __restrict__ Wii,
                                             const float* __restrict__ br,
                                             const float* __restrict__ bi,
                                             float* __restrict__ xrp,
                                             float* __restrict__ xip)
{
  const int lane = threadIdx.x & 63;
  const int wv   = threadIdx.x >> 6;
  const size_t row = (size_t)blockIdx.x * 4 + wv;
  const float* xp = X + row * Id + lane * 8;
  float4 x0 = *(const float4*)(xp);
  float4 x1 = *(const float4*)(xp + 4);
  float4 r0 = *(const float4*)(Wir + lane * 8);
  float4 r1 = *(const float4*)(Wir + lane * 8 + 4);
  float4 i0 = *(const float4*)(Wii + lane * 8);
  float4 i1 = *(const float4*)(Wii + lane * 8 + 4);
  float sr = x0.x*r0.x + x0.y*r0.y + x0.z*r0.z + x0.w*r0.w
           + x1.x*r1.x + x1.y*r1.y + x1.z*r1.z + x1.w*r1.w;
  float si = x0.x*i0.x + x0.y*i0.y + x0.z*i0.z + x0.w*i0.w
           + x1.x*i1.x + x1.y*i1.y + x1.z*i1.z + x1.w*i1.w;
  #pragma unroll
  for (int o = 32; o; o >>= 1) { sr += __shfl_xor(sr, o, 64); si += __shfl_xor(si, o, 64); }
  if (lane == 0) { xrp[row] = sr + br[0]; xip[row] = si + bi[0]; }
}

// ---------------------------------------------------------------------------
// K2: persistent scan, 8 blocks x 1024 threads (16 waves), block-local only.
//  - full W_hh resident in VGPRs: wave w owns 32 columns (2 n-tiles), bf16
//    hi/lo B-fragments (3-term split MFMA == fp32-class accuracy)
//  - h for the group's 16 batches entirely in LDS (fp32 + swizzled bf16 hi/lo)
//  - NO cross-block exchange, NO threadfence: 3 barriers per step
//  - xh lives in d_out; slot t read (prefetched at t-1) then overwritten
// ---------------------------------------------------------------------------
__global__ __launch_bounds__(1024) void k_scan(
    const float* __restrict__ xr, const float* __restrict__ xi,
    const float* __restrict__ Whh, const float* __restrict__ Whr,
    const float* __restrict__ Whi,
    float* __restrict__ hs, float* __restrict__ hlast)
{
  const int g    = blockIdx.x;       // batch group
  const int tid  = threadIdx.x;
  const int lane = tid & 63;
  const int w    = tid >> 6;         // wave 0..15: owns H columns [w*32, w*32+32)
  const int n16  = lane & 15, kq = lane >> 4;
  const int bBase = g * BB;

  __shared__ __align__(16) float hsm[BB][Hd];              // h_t fp32
  __shared__ __align__(16) unsigned short hhi[BB * Hd];    // h_t bf16 hi (swizzled)
  __shared__ __align__(16) unsigned short hlo[BB * Hd];    // h_t bf16 lo (swizzled)
  __shared__ __align__(16) float whr_s[Hd];
  __shared__ __align__(16) float whi_s[Hd];
  __shared__ float zbuf[BB], rbuf[BB];

  if (tid < Hd) { whr_s[tid] = Whr[tid]; whi_s[tid] = Whi[tid]; }
  for (int i = tid; i < BB * Hd / 4; i += 1024) ((float4*)hsm)[i] = make_float4(0,0,0,0);
  for (int i = tid; i < BB * Hd / 2; i += 1024) { ((unsigned int*)hhi)[i] = 0u; ((unsigned int*)hlo)[i] = 0u; }

  // ---- preload W_hh B-fragments: wave w -> cols w*32 + {nt*16 + n16} ----
  // B-frag: lane holds B[k=kt*32+kq*8+i][n]
  short8 wfh0[16], wfl0[16], wfh1[16], wfl1[16];
  {
    const float* wp = Whh + (size_t)(w * 32 + n16);
    #pragma unroll
    for (int kt = 0; kt < 16; ++kt) {
      short8 ph0, pl0, ph1, pl1;
      #pragma unroll
      for (int i = 0; i < 8; ++i) {
        size_t k = (size_t)(kt * 32 + kq * 8 + i);
        unsigned short h, l;
        bf16_split(wp[k * Hd], h, l);        ph0[i] = (short)h; pl0[i] = (short)l;
        bf16_split(wp[k * Hd + 16], h, l);   ph1[i] = (short)h; pl1[i] = (short)l;
      }
      wfh0[kt] = ph0; wfl0[kt] = pl0; wfh1[kt] = ph1; wfl1[kt] = pl1;
    }
  }
  __syncthreads();

  // ---- per-thread prefetch state (one step ahead) ----
  float xh_cur[2][4], xh_nxt[2][4];
  #pragma unroll
  for (int nt = 0; nt < 2; ++nt)
    #pragma unroll
    for (int r = 0; r < 4; ++r)
      xh_cur[nt][r] = hs[((size_t)(bBase + kq * 4 + r) * Sd + 0) * Hd + w * 32 + nt * 16 + n16];
  float xrc = 0.f, xic = 0.f;
  if (lane == 0) { xrc = xr[(size_t)(bBase + w) * Sd]; xic = xi[(size_t)(bBase + w) * Sd]; }

  for (int t = 0; t < Sd; ++t) {
    // ---------- gates: wave w handles batch w over full H ----------
    {
      float sr = 0.f, si = 0.f;
      #pragma unroll
      for (int u = 0; u < 2; ++u) {
        float4 hv = *(float4*)&hsm[w][lane * 8 + u * 4];
        float4 wr4 = *(float4*)&whr_s[lane * 8 + u * 4];
        float4 wi4 = *(float4*)&whi_s[lane * 8 + u * 4];
        sr += hv.x*wr4.x + hv.y*wr4.y + hv.z*wr4.z + hv.w*wr4.w;
        si += hv.x*wi4.x + hv.y*wi4.y + hv.z*wi4.z + hv.w*wi4.w;
      }
      #pragma unroll
      for (int o = 32; o; o >>= 1) { sr += __shfl_xor(sr, o, 64); si += __shfl_xor(si, o, 64); }
      if (lane == 0) {
        zbuf[w] = 1.f / (1.f + __expf(-(xrc + sr)));
        rbuf[w] = 1.f / (1.f + __expf(-(xic + si)));
      }
    }
    __syncthreads();

    // ---------- prefetch step t+1 (consumed next iteration) ----------
    const int tt = (t + 1 < Sd) ? (t + 1) : t;
    float xrn = 0.f, xin = 0.f;
    if (lane == 0) {
      xrn = xr[(size_t)(bBase + w) * Sd + tt];
      xin = xi[(size_t)(bBase + w) * Sd + tt];
    }
    #pragma unroll
    for (int nt = 0; nt < 2; ++nt)
      #pragma unroll
      for (int r = 0; r < 4; ++r)
        xh_nxt[nt][r] = hs[((size_t)(bBase + kq * 4 + r) * Sd + tt) * Hd + w * 32 + nt * 16 + n16];

    // ---------- v = h @ Whh[:, wave cols], 3-term bf16 split ----------
    f32x4 a00={0,0,0,0}, a01={0,0,0,0}, a02={0,0,0,0};
    f32x4 a10={0,0,0,0}, a11={0,0,0,0}, a12={0,0,0,0};
    {
      const int abase = (lane & 15) * 1024 + kq * 16;
      const int sw = ((lane & 15) & 7) << 4;
      #pragma unroll
      for (int kt = 0; kt < 16; ++kt) {
        int off = (abase + kt * 64) ^ sw;
        short8 ah = *(short8*)((char*)hhi + off);
        short8 al = *(short8*)((char*)hlo + off);
        a00 = __builtin_amdgcn_mfma_f32_16x16x32_bf16(ah, wfh0[kt], a00, 0,0,0);
        a01 = __builtin_amdgcn_mfma_f32_16x16x32_bf16(ah, wfl0[kt], a01, 0,0,0);
        a02 = __builtin_amdgcn_mfma_f32_16x16x32_bf16(al, wfh0[kt], a02, 0,0,0);
        a10 = __builtin_amdgcn_mfma_f32_16x16x32_bf16(ah, wfh1[kt], a10, 0,0,0);
        a11 = __builtin_amdgcn_mfma_f32_16x16x32_bf16(ah, wfl1[kt], a11, 0,0,0);
        a12 = __builtin_amdgcn_mfma_f32_16x16x32_bf16(al, wfh1[kt], a12, 0,0,0);
      }
    }

    // ---------- epilogue: n = tanh(xh + r*v); h' = z*h + (1-z)*n ----------
    float hn[2][4];
    #pragma unroll
    for (int nt = 0; nt < 2; ++nt) {
      f32x4 v4 = nt ? (a10 + a11 + a12) : (a00 + a01 + a02);
      int j = w * 32 + nt * 16 + n16;
      #pragma unroll
      for (int r = 0; r < 4; ++r) {
        int row = kq * 4 + r;               // C-layout: col=lane&15, row=kq*4+r
        float rr = rbuf[row], zz = zbuf[row];
        float xv = xh_cur[nt][r] + rr * v4[r];
        float nn = 1.f - 2.f / (__expf(2.f * xv) + 1.f);   // tanh
        float hnew = zz * hsm[row][j] + (1.f - zz) * nn;
        hs[((size_t)(bBase + row) * Sd + t) * Hd + j] = hnew;
        if (t == Sd - 1) hlast[(size_t)(bBase + row) * Hd + j] = hnew;
        hn[nt][r] = hnew;
      }
    }
    __syncthreads();                        // all hhi/hlo reads of step t done

    // ---------- write h_{t+1} into LDS (fp32 + swizzled bf16 hi/lo) ----------
    #pragma unroll
    for (int nt = 0; nt < 2; ++nt) {
      int j = w * 32 + nt * 16 + n16;
      #pragma unroll
      for (int r = 0; r < 4; ++r) {
        int row = kq * 4 + r;
        float hnew = hn[nt][r];
        hsm[row][j] = hnew;
        unsigned short hb, lb; bf16_split(hnew, hb, lb);
        int off = (row * 1024 + j * 2) ^ ((row & 7) << 4);
        *(unsigned short*)((char*)hhi + off) = hb;
        *(unsigned short*)((char*)hlo + off) = lb;
      }
    }
    __syncthreads();

    #pragma unroll
    for (int nt = 0; nt < 2; ++nt)
      #pragma unroll
      for (int r = 0; r < 4; ++r) xh_cur[nt][r] = xh_nxt[nt][r];
    xrc = xrn; xic = xin;
  }
}

// ---------------------------------------------------------------------------
extern "C" void kernel_launch(void* const* d_in, const int* in_sizes, int n_in,
                              void* d_out, int out_size, void* d_ws, size_t ws_size,
                              hipStream_t stream)
{
  const float* X    = (const float*)d_in[0];
  const float* Wih  = (const float*)d_in[1];
  const float* Whh  = (const float*)d_in[2];
  const float* Wir  = (const float*)d_in[3];
  const float* Whr  = (const float*)d_in[4];
  const float* Wii  = (const float*)d_in[5];
  const float* Whi  = (const float*)d_in[6];
  const float* bh   = (const float*)d_in[7];
  const float* br   = (const float*)d_in[8];
  const float* bi   = (const float*)d_in[9];
  (void)in_sizes; (void)n_in; (void)out_size; (void)ws_size;

  float* out   = (float*)d_out;
  float* hlast = out + (size_t)Bd * Sd * Hd;

  // ws layout: xr (512KB) | xi (512KB)
  char*  ws = (char*)d_ws;
  float* xr = (float*)(ws);
  float* xi = (float*)(ws + (size_t)Bd * Sd * 4);

  k_xh  <<<dim3(4096),        dim3(256),  0, stream>>>(X, Wih, bh, out);
  k_xri <<<dim3(Bd * Sd / 4), dim3(256),  0, stream>>>(X, Wir, Wii, br, bi, xr, xi);
  k_scan<<<dim3(NG),          dim3(1024), 0, stream>>>(xr, xi, Whh, Whr, Whi, out, hlast);
}